// Round 1
// baseline (128.249 us; speedup 1.0000x reference)
//
#include <hip/hip_runtime.h>
#include <cstdint>
#include <cstddef>

typedef __bf16 bf16x8 __attribute__((ext_vector_type(8)));
typedef float  f32x4  __attribute__((ext_vector_type(4)));

#define N_ROWS 8192
#define KDIM   256
#define TEMP_INV 2.0f
#define LOG2E  1.4426950408889634f

__device__ __forceinline__ ushort f2bf(float x) {
    // round-to-nearest-even f32 -> bf16 (inputs finite)
    uint32_t u = __float_as_uint(x);
    u += 0x7fffu + ((u >> 16) & 1u);
    return (ushort)(u >> 16);
}

// ---------------- Kernel A: label ranking / permutation (1 block, deterministic)
__global__ void build_perm(const int* __restrict__ label, int* __restrict__ perm,
                           int* __restrict__ labelPerm, int* __restrict__ classStart,
                           int* __restrict__ cumTiles)
{
    __shared__ int lcnt[256][10];
    __shared__ int cstart[11];
    __shared__ int ccount[10];
    const int tid = threadIdx.x;
    const int beg = tid * 32, end = beg + 32;

    int loc[10] = {0,0,0,0,0,0,0,0,0,0};
    for (int i = beg; i < end; ++i) {
        int c = label[i]; c = (c < 0) ? 0 : (c > 9 ? 9 : c);
        loc[c]++;
    }
    #pragma unroll
    for (int c = 0; c < 10; ++c) lcnt[tid][c] = loc[c];
    __syncthreads();

    if (tid < 10) {
        int run = 0;
        for (int t = 0; t < 256; ++t) { int v = lcnt[t][tid]; lcnt[t][tid] = run; run += v; }
        ccount[tid] = run;
    }
    __syncthreads();

    if (tid == 0) {
        int run = 0, runT = 0;
        for (int c = 0; c < 10; ++c) {
            cstart[c] = run; classStart[c] = run;
            int tpc = (ccount[c] + 127) >> 7;
            cumTiles[c] = runT;
            run  += ccount[c];
            runT += tpc * tpc;
        }
        cstart[10] = run; classStart[10] = run; cumTiles[10] = runT;
    }
    __syncthreads();

    int ofs[10];
    #pragma unroll
    for (int c = 0; c < 10; ++c) ofs[c] = lcnt[tid][c];
    for (int i = beg; i < end; ++i) {
        int c = label[i]; c = (c < 0) ? 0 : (c > 9 ? 9 : c);
        int pos = cstart[c] + ofs[c]++;
        perm[pos] = i;
        labelPerm[pos] = c;
    }
}

// ---------------- Kernel B: normalize + permute + bf16 cast (1 wave / row)
__global__ void normalize_rows(const float* __restrict__ logits, const int* __restrict__ perm,
                               ushort* __restrict__ xn)
{
    const int p = blockIdx.x;
    const int lane = threadIdx.x;  // 64
    const int old = perm[p];
    float4 v = reinterpret_cast<const float4*>(logits + (size_t)old * KDIM)[lane];
    float ss = v.x*v.x + v.y*v.y + v.z*v.z + v.w*v.w;
    #pragma unroll
    for (int off = 32; off >= 1; off >>= 1) ss += __shfl_xor(ss, off, 64);
    float inv = 1.0f / fmaxf(sqrtf(ss), 1e-8f);
    ushort4 o;
    o.x = f2bf(v.x * inv); o.y = f2bf(v.y * inv);
    o.z = f2bf(v.z * inv); o.w = f2bf(v.w * inv);
    reinterpret_cast<ushort4*>(xn + (size_t)p * KDIM)[lane] = o;
}

// ---------------- shared GEMM core: 128x128 tile, K=256, BK=64, 4 waves
__device__ __forceinline__ void stage_tiles(const ushort* __restrict__ xn,
        int rowBase, int colBase, int kb, ushort* As, ushort* Bs, int wave, int lane)
{
    #pragma unroll
    for (int it = 0; it < 4; ++it) {
        int ci = it * 256 + wave * 64 + lane;          // 16B chunk index in [0,1024)
        int rowA = rowBase + (ci >> 3); if (rowA > N_ROWS - 1) rowA = N_ROWS - 1;
        int rowB = colBase + (ci >> 3); if (rowB > N_ROWS - 1) rowB = N_ROWS - 1;
        const ushort* gA = xn + (size_t)rowA * KDIM + kb + (ci & 7) * 8;
        const ushort* gB = xn + (size_t)rowB * KDIM + kb + (ci & 7) * 8;
        ushort* lA = As + (size_t)(it * 256 + wave * 64) * 8;  // wave-uniform LDS base
        ushort* lB = Bs + (size_t)(it * 256 + wave * 64) * 8;
        __builtin_amdgcn_global_load_lds((const __attribute__((address_space(1))) void*)gA,
                                         (__attribute__((address_space(3))) void*)lA, 16, 0, 0);
        __builtin_amdgcn_global_load_lds((const __attribute__((address_space(1))) void*)gB,
                                         (__attribute__((address_space(3))) void*)lB, 16, 0, 0);
    }
}

__device__ __forceinline__ void compute_step(const ushort* As, const ushort* Bs,
        f32x4 acc[4][4], int wave, int lane)
{
    const int wr = wave >> 1, wc = wave & 1;
    const int lrow = lane & 15;
    const int kgrp = lane >> 4;
    #pragma unroll
    for (int kk = 0; kk < 2; ++kk) {
        bf16x8 a[4], b[4];
        const int ko = kk * 32 + kgrp * 8;
        #pragma unroll
        for (int mi = 0; mi < 4; ++mi)
            a[mi] = *reinterpret_cast<const bf16x8*>(As + (size_t)(wr*64 + mi*16 + lrow) * 64 + ko);
        #pragma unroll
        for (int ni = 0; ni < 4; ++ni)
            b[ni] = *reinterpret_cast<const bf16x8*>(Bs + (size_t)(wc*64 + ni*16 + lrow) * 64 + ko);
        #pragma unroll
        for (int mi = 0; mi < 4; ++mi)
            #pragma unroll
            for (int ni = 0; ni < 4; ++ni)
                acc[mi][ni] = __builtin_amdgcn_mfma_f32_16x16x32_bf16(a[mi], b[ni], acc[mi][ni], 0, 0, 0);
    }
}

// ---------------- Kernel C: full GEMM + exp epilogue -> per-tile row partials of T and P
__global__ __launch_bounds__(256) void phase1_gemm(const ushort* __restrict__ xn,
        const int* __restrict__ labelPerm, float* __restrict__ pT, float* __restrict__ pP)
{
    __shared__ ushort As[128 * 64];
    __shared__ ushort Bs[128 * 64];
    __shared__ int rowLab[128], colLab[128];
    __shared__ float redT[128][2], redP[128][2];

    const int tid = threadIdx.x;
    const int wave = tid >> 6, lane = tid & 63;
    const int bi = blockIdx.y, bj = blockIdx.x;
    const int rowBase = bi * 128, colBase = bj * 128;

    if (tid < 128) rowLab[tid] = labelPerm[rowBase + tid];
    else           colLab[tid - 128] = labelPerm[colBase + (tid - 128)];

    f32x4 acc[4][4] = {};
    for (int kt = 0; kt < 4; ++kt) {
        stage_tiles(xn, rowBase, colBase, kt * 64, As, Bs, wave, lane);
        __syncthreads();
        compute_step(As, Bs, acc, wave, lane);
        __syncthreads();
    }

    const int wr = wave >> 1, wc = wave & 1;
    const int lrow = lane & 15, lgrp = lane >> 4;
    #pragma unroll
    for (int mi = 0; mi < 4; ++mi) {
        #pragma unroll
        for (int reg = 0; reg < 4; ++reg) {
            const int tr = wr * 64 + mi * 16 + lgrp * 4 + reg;
            const int r = rowBase + tr;
            float t = 0.f, p = 0.f;
            #pragma unroll
            for (int ni = 0; ni < 4; ++ni) {
                const int tc = wc * 64 + ni * 16 + lrow;
                const int cg = colBase + tc;
                float sim = acc[mi][ni][reg];
                float e = (r == cg) ? 0.f : __builtin_amdgcn_exp2f(sim * (TEMP_INV * LOG2E));
                t += e;
                p += (rowLab[tr] == colLab[tc]) ? e : 0.f;
            }
            #pragma unroll
            for (int off = 1; off < 16; off <<= 1) {
                t += __shfl_xor(t, off, 64);
                p += __shfl_xor(p, off, 64);
            }
            if (lrow == 0) { redT[tr][wc] = t; redP[tr][wc] = p; }
        }
    }
    __syncthreads();
    if (tid < 128) {
        pT[(size_t)bj * N_ROWS + rowBase + tid] = redT[tid][0] + redT[tid][1];
        pP[(size_t)bj * N_ROWS + rowBase + tid] = redP[tid][0] + redP[tid][1];
    }
}

// ---------------- Kernel C2: D_i = T_i - P_i (deterministic fixed-order sum)
__global__ void phase2_rowsum(const float* __restrict__ pT, const float* __restrict__ pP,
                              float* __restrict__ Darr)
{
    const int i = blockIdx.x * blockDim.x + threadIdx.x;
    if (i >= N_ROWS) return;
    float t = 0.f, p = 0.f;
    for (int tj = 0; tj < 64; ++tj) {
        t += pT[(size_t)tj * N_ROWS + i];
        p += pP[(size_t)tj * N_ROWS + i];
    }
    Darr[i] = t - p;
}

// ---------------- Kernel D: same-class diagonal block tiles -> log terms
__global__ __launch_bounds__(256) void phase3_loss(const ushort* __restrict__ xn,
        const float* __restrict__ Darr, const int* __restrict__ classStart,
        const int* __restrict__ cumTiles, float* __restrict__ partial)
{
    __shared__ ushort As[128 * 64];
    __shared__ ushort Bs[128 * 64];
    __shared__ float red[256];

    const int b = blockIdx.x;
    const int nTiles = cumTiles[10];
    if (b >= nTiles) return;

    int c = 0;
    while (c < 9 && b >= cumTiles[c + 1]) ++c;
    const int s = classStart[c], e = classStart[c + 1];
    const int nc = e - s;
    const int tps = (nc + 127) >> 7;
    const int lt = b - cumTiles[c];
    const int ti = lt / tps, tj = lt - ti * tps;
    const int rowBase = s + ti * 128, colBase = s + tj * 128;

    const int tid = threadIdx.x;
    const int wave = tid >> 6, lane = tid & 63;

    f32x4 acc[4][4] = {};
    for (int kt = 0; kt < 4; ++kt) {
        stage_tiles(xn, rowBase, colBase, kt * 64, As, Bs, wave, lane);
        __syncthreads();
        compute_step(As, Bs, acc, wave, lane);
        __syncthreads();
    }

    const int wr = wave >> 1, wc = wave & 1;
    const int lrow = lane & 15, lgrp = lane >> 4;
    float lsum = 0.f;
    #pragma unroll
    for (int mi = 0; mi < 4; ++mi) {
        #pragma unroll
        for (int reg = 0; reg < 4; ++reg) {
            const int r = rowBase + wr * 64 + mi * 16 + lgrp * 4 + reg;
            if (r < e) {
                const float Dr = Darr[r];
                #pragma unroll
                for (int ni = 0; ni < 4; ++ni) {
                    const int cg = colBase + wc * 64 + ni * 16 + lrow;
                    if (cg < e && cg != r) {
                        float sim = acc[mi][ni][reg];
                        float ev = __builtin_amdgcn_exp2f(sim * (TEMP_INV * LOG2E));
                        lsum += __logf(ev + Dr) - TEMP_INV * sim;
                    }
                }
            }
        }
    }
    red[tid] = lsum;
    __syncthreads();
    for (int st = 128; st > 0; st >>= 1) {
        if (tid < st) red[tid] += red[tid + st];
        __syncthreads();
    }
    if (tid == 0) partial[b] = red[0];
}

// ---------------- Kernel E: deterministic final reduction + scale
__global__ void phase4_final(const float* __restrict__ partial, const int* __restrict__ cumTiles,
                             float* __restrict__ out)
{
    __shared__ float red[256];
    const int tid = threadIdx.x;
    const int nTiles = cumTiles[10];
    float s = 0.f;
    for (int i = tid; i < nTiles; i += 256) s += partial[i];
    red[tid] = s;
    __syncthreads();
    for (int st = 128; st > 0; st >>= 1) {
        if (tid < st) red[tid] += red[tid + st];
        __syncthreads();
    }
    if (tid == 0) out[0] = red[0] * (1.0f / 16384.0f);
}

extern "C" void kernel_launch(void* const* d_in, const int* in_sizes, int n_in,
                              void* d_out, int out_size, void* d_ws, size_t ws_size,
                              hipStream_t stream)
{
    const float* logits = (const float*)d_in[0];
    const int*   label  = (const int*)d_in[1];
    float* out = (float*)d_out;

    char* ws = (char*)d_ws;
    ushort* xn        = (ushort*)(ws);                          // 8192*256*2 = 4 MB
    float*  pT        = (float*)(ws + (4u << 20));              // 64*8192*4 = 2 MB
    float*  pP        = (float*)(ws + (6u << 20));              // 2 MB
    float*  Darr      = (float*)(ws + (8u << 20));              // 32 KB
    int*    perm      = (int*)(ws + (8u << 20) + (64u << 10));  // 32 KB
    int*    labelPerm = (int*)(ws + (8u << 20) + (128u << 10)); // 32 KB
    int*    classStart= (int*)(ws + (8u << 20) + (192u << 10)); // 64 B
    int*    cumTiles  = (int*)(ws + (8u << 20) + (192u << 10) + 256); // 64 B
    float*  partial   = (float*)(ws + (8u << 20) + (256u << 10));     // 16 KB

    hipLaunchKernelGGL(build_perm, dim3(1), dim3(256), 0, stream,
                       label, perm, labelPerm, classStart, cumTiles);
    hipLaunchKernelGGL(normalize_rows, dim3(8192), dim3(64), 0, stream,
                       logits, perm, xn);
    hipLaunchKernelGGL(phase1_gemm, dim3(64, 64), dim3(256), 0, stream,
                       xn, labelPerm, pT, pP);
    hipLaunchKernelGGL(phase2_rowsum, dim3(32), dim3(256), 0, stream,
                       pT, pP, Darr);
    hipLaunchKernelGGL(phase3_loss, dim3(4096), dim3(256), 0, stream,
                       xn, Darr, classStart, cumTiles, partial);
    hipLaunchKernelGGL(phase4_final, dim3(1), dim3(256), 0, stream,
                       partial, cumTiles, out);
}

// Round 2
// 100.503 us; speedup vs baseline: 1.2761x; 1.2761x over previous
//
#include <hip/hip_runtime.h>
#include <cstdint>
#include <cstddef>

typedef __bf16 bf16x8 __attribute__((ext_vector_type(8)));
typedef float  f32x4  __attribute__((ext_vector_type(4)));

#define N_ROWS 8192
#define KDIM   256
#define TEMP_INV 2.0f
#define LOG2E  1.4426950408889634f
#define EXPC   (TEMP_INV * LOG2E)

__device__ __forceinline__ ushort f2bf(float x) {
    uint32_t u = __float_as_uint(x);
    u += 0x7fffu + ((u >> 16) & 1u);
    return (ushort)(u >> 16);
}

// ---------------- Kernel A: label ranking / permutation (1 block, deterministic)
__global__ void build_perm(const int* __restrict__ label, int* __restrict__ perm,
                           int* __restrict__ labelPerm, int* __restrict__ classStart,
                           int* __restrict__ cumTiles)
{
    __shared__ int lcnt[256][10];
    __shared__ int cstart[11];
    __shared__ int ccount[10];
    const int tid = threadIdx.x;
    const int beg = tid * 32, end = beg + 32;

    int loc[10] = {0,0,0,0,0,0,0,0,0,0};
    for (int i = beg; i < end; ++i) {
        int c = label[i]; c = (c < 0) ? 0 : (c > 9 ? 9 : c);
        loc[c]++;
    }
    #pragma unroll
    for (int c = 0; c < 10; ++c) lcnt[tid][c] = loc[c];
    __syncthreads();

    if (tid < 10) {
        int run = 0;
        for (int t = 0; t < 256; ++t) { int v = lcnt[t][tid]; lcnt[t][tid] = run; run += v; }
        ccount[tid] = run;
    }
    __syncthreads();

    if (tid == 0) {
        int run = 0, runT = 0;
        for (int c = 0; c < 10; ++c) {
            cstart[c] = run; classStart[c] = run;
            int tpc = (ccount[c] + 127) >> 7;
            cumTiles[c] = runT;
            run  += ccount[c];
            runT += tpc * tpc;
        }
        cstart[10] = run; classStart[10] = run; cumTiles[10] = runT;
    }
    __syncthreads();

    int ofs[10];
    #pragma unroll
    for (int c = 0; c < 10; ++c) ofs[c] = lcnt[tid][c];
    for (int i = beg; i < end; ++i) {
        int c = label[i]; c = (c < 0) ? 0 : (c > 9 ? 9 : c);
        int pos = cstart[c] + ofs[c]++;
        perm[pos] = i;
        labelPerm[pos] = c;
    }
}

// ---------------- Kernel B: normalize + permute + bf16 cast (1 wave / row)
__global__ void normalize_rows(const float* __restrict__ logits, const int* __restrict__ perm,
                               ushort* __restrict__ xn)
{
    const int p = blockIdx.x;
    const int lane = threadIdx.x;  // 64
    const int old = perm[p];
    float4 v = reinterpret_cast<const float4*>(logits + (size_t)old * KDIM)[lane];
    float ss = v.x*v.x + v.y*v.y + v.z*v.z + v.w*v.w;
    #pragma unroll
    for (int off = 32; off >= 1; off >>= 1) ss += __shfl_xor(ss, off, 64);
    float inv = 1.0f / fmaxf(sqrtf(ss), 1e-8f);
    ushort4 o;
    o.x = f2bf(v.x * inv); o.y = f2bf(v.y * inv);
    o.z = f2bf(v.z * inv); o.w = f2bf(v.w * inv);
    reinterpret_cast<ushort4*>(xn + (size_t)p * KDIM)[lane] = o;
}

// ---------------- shared GEMM core: 128x128 tile, K=256, BK=64, 4 waves
// LDS layout: linear [128 rows][8 chunks of 16B], but the STORED chunk for
// (row, logical chunk c) is cs = c ^ (row&7)  (T2 swizzle). global_load_lds
// writes linearly (wave-uniform base + lane*16), so the swizzle is applied by
// pre-permuting the GLOBAL source chunk (rule #21), and re-applied on ds_read.
__device__ __forceinline__ void stage_tiles(const ushort* __restrict__ xn,
        int rowBase, int colBase, int kb, ushort* As, ushort* Bs, int wave, int lane)
{
    #pragma unroll
    for (int it = 0; it < 4; ++it) {
        int ci = it * 256 + wave * 64 + lane;          // 16B chunk index in [0,1024)
        int row = ci >> 3;
        int c = (ci & 7) ^ (row & 7);                  // logical chunk for this slot
        int rowA = rowBase + row; if (rowA > N_ROWS - 1) rowA = N_ROWS - 1;
        int rowB = colBase + row; if (rowB > N_ROWS - 1) rowB = N_ROWS - 1;
        const ushort* gA = xn + (size_t)rowA * KDIM + kb + c * 8;
        const ushort* gB = xn + (size_t)rowB * KDIM + kb + c * 8;
        ushort* lA = As + (size_t)(it * 256 + wave * 64) * 8;  // wave-uniform LDS base
        ushort* lB = Bs + (size_t)(it * 256 + wave * 64) * 8;
        __builtin_amdgcn_global_load_lds((const __attribute__((address_space(1))) void*)gA,
                                         (__attribute__((address_space(3))) void*)lA, 16, 0, 0);
        __builtin_amdgcn_global_load_lds((const __attribute__((address_space(1))) void*)gB,
                                         (__attribute__((address_space(3))) void*)lB, 16, 0, 0);
    }
}

__device__ __forceinline__ void compute_step(const ushort* As, const ushort* Bs,
        f32x4 acc[4][4], int wave, int lane)
{
    const int wr = wave >> 1, wc = wave & 1;
    const int lrow = lane & 15;
    const int kgrp = lane >> 4;
    #pragma unroll
    for (int kk = 0; kk < 2; ++kk) {
        bf16x8 a[4], b[4];
        const int c = kk * 4 + kgrp;                   // logical 16B chunk
        #pragma unroll
        for (int mi = 0; mi < 4; ++mi) {
            const int row = wr*64 + mi*16 + lrow;
            a[mi] = *reinterpret_cast<const bf16x8*>(As + (size_t)row * 64 + ((c ^ (row & 7)) * 8));
        }
        #pragma unroll
        for (int ni = 0; ni < 4; ++ni) {
            const int row = wc*64 + ni*16 + lrow;
            b[ni] = *reinterpret_cast<const bf16x8*>(Bs + (size_t)row * 64 + ((c ^ (row & 7)) * 8));
        }
        #pragma unroll
        for (int mi = 0; mi < 4; ++mi)
            #pragma unroll
            for (int ni = 0; ni < 4; ++ni)
                acc[mi][ni] = __builtin_amdgcn_mfma_f32_16x16x32_bf16(a[mi], b[ni], acc[mi][ni], 0, 0, 0);
    }
}

// ---------------- Kernel C: upper-triangular tiles (bi<=bj) + exp epilogue.
// Off-diagonal tiles emit BOTH row partials (slice bj, rows of block bi) and
// column partials (slice bi, rows of block bj) via e_ij == e_ji symmetry.
__global__ __launch_bounds__(256) void phase1_gemm(const ushort* __restrict__ xn,
        const int* __restrict__ labelPerm, float* __restrict__ pT, float* __restrict__ pP)
{
    __shared__ ushort As[128 * 64];
    __shared__ ushort Bs[128 * 64];
    __shared__ int rowLab[128], colLab[128];
    __shared__ float redT[128][2], redP[128][2];
    __shared__ float redCT[128][2], redCP[128][2];

    const int tid = threadIdx.x;
    const int wave = tid >> 6, lane = tid & 63;

    // decode upper-triangular tile index -> (bi, bj), bi <= bj
    int t = blockIdx.x, bi = 0;
    while (t >= 64 - bi) { t -= 64 - bi; ++bi; }
    const int bj = bi + t;
    const bool isDiag = (bi == bj);
    const int rowBase = bi * 128, colBase = bj * 128;

    if (tid < 128) rowLab[tid] = labelPerm[rowBase + tid];
    else           colLab[tid - 128] = labelPerm[colBase + (tid - 128)];

    f32x4 acc[4][4] = {};
    for (int kt = 0; kt < 4; ++kt) {
        stage_tiles(xn, rowBase, colBase, kt * 64, As, Bs, wave, lane);
        __syncthreads();
        compute_step(As, Bs, acc, wave, lane);
        __syncthreads();
    }

    const int wr = wave >> 1, wc = wave & 1;
    const int lrow = lane & 15, lgrp = lane >> 4;
    float ct[4] = {0.f,0.f,0.f,0.f}, cp[4] = {0.f,0.f,0.f,0.f};
    #pragma unroll
    for (int mi = 0; mi < 4; ++mi) {
        #pragma unroll
        for (int reg = 0; reg < 4; ++reg) {
            const int tr = wr * 64 + mi * 16 + lgrp * 4 + reg;
            const int r = rowBase + tr;
            float trow = 0.f, prow = 0.f;
            #pragma unroll
            for (int ni = 0; ni < 4; ++ni) {
                const int tc = wc * 64 + ni * 16 + lrow;
                const int cg = colBase + tc;
                float sim = acc[mi][ni][reg];
                float e = __builtin_amdgcn_exp2f(sim * EXPC);
                if (isDiag && r == cg) e = 0.f;
                const bool same = (rowLab[tr] == colLab[tc]);
                trow += e;
                prow += same ? e : 0.f;
                if (!isDiag) {
                    ct[ni] += e;
                    cp[ni] += same ? e : 0.f;
                }
            }
            #pragma unroll
            for (int off = 1; off < 16; off <<= 1) {
                trow += __shfl_xor(trow, off, 64);
                prow += __shfl_xor(prow, off, 64);
            }
            if (lrow == 0) { redT[tr][wc] = trow; redP[tr][wc] = prow; }
        }
    }
    if (!isDiag) {
        #pragma unroll
        for (int ni = 0; ni < 4; ++ni) {
            ct[ni] += __shfl_xor(ct[ni], 16, 64);
            ct[ni] += __shfl_xor(ct[ni], 32, 64);
            cp[ni] += __shfl_xor(cp[ni], 16, 64);
            cp[ni] += __shfl_xor(cp[ni], 32, 64);
            if (lgrp == 0) {
                const int tc = wc * 64 + ni * 16 + lrow;
                redCT[tc][wr] = ct[ni];
                redCP[tc][wr] = cp[ni];
            }
        }
    }
    __syncthreads();
    if (tid < 128) {
        pT[(size_t)bj * N_ROWS + rowBase + tid] = redT[tid][0] + redT[tid][1];
        pP[(size_t)bj * N_ROWS + rowBase + tid] = redP[tid][0] + redP[tid][1];
        if (!isDiag) {
            pT[(size_t)bi * N_ROWS + colBase + tid] = redCT[tid][0] + redCT[tid][1];
            pP[(size_t)bi * N_ROWS + colBase + tid] = redCP[tid][0] + redCP[tid][1];
        }
    }
}

// ---------------- Kernel C2: D_i = T_i - P_i (deterministic fixed-order sum)
__global__ void phase2_rowsum(const float* __restrict__ pT, const float* __restrict__ pP,
                              float* __restrict__ Darr)
{
    const int i = blockIdx.x * blockDim.x + threadIdx.x;
    if (i >= N_ROWS) return;
    float t = 0.f, p = 0.f;
    for (int tj = 0; tj < 64; ++tj) {
        t += pT[(size_t)tj * N_ROWS + i];
        p += pP[(size_t)tj * N_ROWS + i];
    }
    Darr[i] = t - p;
}

// ---------------- Kernel D: same-class diagonal block tiles -> log terms
__global__ __launch_bounds__(256) void phase3_loss(const ushort* __restrict__ xn,
        const float* __restrict__ Darr, const int* __restrict__ classStart,
        const int* __restrict__ cumTiles, float* __restrict__ partial)
{
    __shared__ ushort As[128 * 64];
    __shared__ ushort Bs[128 * 64];
    __shared__ float red[256];

    const int b = blockIdx.x;
    const int nTiles = cumTiles[10];
    if (b >= nTiles) return;

    int c = 0;
    while (c < 9 && b >= cumTiles[c + 1]) ++c;
    const int s = classStart[c], e = classStart[c + 1];
    const int nc = e - s;
    const int tps = (nc + 127) >> 7;
    const int lt = b - cumTiles[c];
    const int ti = lt / tps, tj = lt - ti * tps;
    const int rowBase = s + ti * 128, colBase = s + tj * 128;

    const int tid = threadIdx.x;
    const int wave = tid >> 6, lane = tid & 63;

    f32x4 acc[4][4] = {};
    for (int kt = 0; kt < 4; ++kt) {
        stage_tiles(xn, rowBase, colBase, kt * 64, As, Bs, wave, lane);
        __syncthreads();
        compute_step(As, Bs, acc, wave, lane);
        __syncthreads();
    }

    const int wr = wave >> 1, wc = wave & 1;
    const int lrow = lane & 15, lgrp = lane >> 4;
    float lsum = 0.f;
    #pragma unroll
    for (int mi = 0; mi < 4; ++mi) {
        #pragma unroll
        for (int reg = 0; reg < 4; ++reg) {
            const int r = rowBase + wr * 64 + mi * 16 + lgrp * 4 + reg;
            if (r < e) {
                const float Dr = Darr[r];
                #pragma unroll
                for (int ni = 0; ni < 4; ++ni) {
                    const int cg = colBase + wc * 64 + ni * 16 + lrow;
                    if (cg < e && cg != r) {
                        float sim = acc[mi][ni][reg];
                        float ev = __builtin_amdgcn_exp2f(sim * EXPC);
                        lsum += __logf(ev + Dr) - TEMP_INV * sim;
                    }
                }
            }
        }
    }
    red[tid] = lsum;
    __syncthreads();
    for (int st = 128; st > 0; st >>= 1) {
        if (tid < st) red[tid] += red[tid + st];
        __syncthreads();
    }
    if (tid == 0) partial[b] = red[0];
}

// ---------------- Kernel E: deterministic final reduction + scale
__global__ void phase4_final(const float* __restrict__ partial, const int* __restrict__ cumTiles,
                             float* __restrict__ out)
{
    __shared__ float red[256];
    const int tid = threadIdx.x;
    const int nTiles = cumTiles[10];
    float s = 0.f;
    for (int i = tid; i < nTiles; i += 256) s += partial[i];
    red[tid] = s;
    __syncthreads();
    for (int st = 128; st > 0; st >>= 1) {
        if (tid < st) red[tid] += red[tid + st];
        __syncthreads();
    }
    if (tid == 0) out[0] = red[0] * (1.0f / 16384.0f);
}

extern "C" void kernel_launch(void* const* d_in, const int* in_sizes, int n_in,
                              void* d_out, int out_size, void* d_ws, size_t ws_size,
                              hipStream_t stream)
{
    const float* logits = (const float*)d_in[0];
    const int*   label  = (const int*)d_in[1];
    float* out = (float*)d_out;

    char* ws = (char*)d_ws;
    ushort* xn        = (ushort*)(ws);                          // 4 MB
    float*  pT        = (float*)(ws + (4u << 20));              // 2 MB
    float*  pP        = (float*)(ws + (6u << 20));              // 2 MB
    float*  Darr      = (float*)(ws + (8u << 20));              // 32 KB
    int*    perm      = (int*)(ws + (8u << 20) + (64u << 10));  // 32 KB
    int*    labelPerm = (int*)(ws + (8u << 20) + (128u << 10)); // 32 KB
    int*    classStart= (int*)(ws + (8u << 20) + (192u << 10)); // 64 B
    int*    cumTiles  = (int*)(ws + (8u << 20) + (192u << 10) + 256); // 64 B
    float*  partial   = (float*)(ws + (8u << 20) + (256u << 10));     // 16 KB

    hipLaunchKernelGGL(build_perm, dim3(1), dim3(256), 0, stream,
                       label, perm, labelPerm, classStart, cumTiles);
    hipLaunchKernelGGL(normalize_rows, dim3(8192), dim3(64), 0, stream,
                       logits, perm, xn);
    hipLaunchKernelGGL(phase1_gemm, dim3(2080), dim3(256), 0, stream,
                       xn, labelPerm, pT, pP);
    hipLaunchKernelGGL(phase2_rowsum, dim3(32), dim3(256), 0, stream,
                       pT, pP, Darr);
    hipLaunchKernelGGL(phase3_loss, dim3(4096), dim3(256), 0, stream,
                       xn, Darr, classStart, cumTiles, partial);
    hipLaunchKernelGGL(phase4_final, dim3(1), dim3(256), 0, stream,
                       partial, cumTiles, out);
}

// Round 3
// 75.259 us; speedup vs baseline: 1.7041x; 1.3354x over previous
//
#include <hip/hip_runtime.h>
#include <cstdint>
#include <cstddef>

typedef __bf16 bf16x8 __attribute__((ext_vector_type(8)));
typedef float  f32x4  __attribute__((ext_vector_type(4)));

#define N_ROWS 8192
#define KDIM   256
#define TEMP_INV 2.0f
#define LOG2E  1.4426950408889634f
#define EXPC   (TEMP_INV * LOG2E)

__device__ __forceinline__ ushort f2bf(float x) {
    uint32_t u = __float_as_uint(x);
    u += 0x7fffu + ((u >> 16) & 1u);
    return (ushort)(u >> 16);
}

// ---------------- Kernel A: label ranking / permutation (1 block, deterministic)
__global__ void build_perm(const int* __restrict__ label, int* __restrict__ perm,
                           int* __restrict__ labelPerm, int* __restrict__ classStart,
                           int* __restrict__ cumTiles)
{
    __shared__ int lcnt[256][10];
    __shared__ int cstart[11];
    __shared__ int ccount[10];
    const int tid = threadIdx.x;
    const int wave = tid >> 6, lane = tid & 63;
    const int beg = tid * 32, end = beg + 32;

    int loc[10] = {0,0,0,0,0,0,0,0,0,0};
    for (int i = beg; i < end; ++i) {
        int c = label[i]; c = (c < 0) ? 0 : (c > 9 ? 9 : c);
        loc[c]++;
    }
    #pragma unroll
    for (int c = 0; c < 10; ++c) lcnt[tid][c] = loc[c];
    __syncthreads();

    // wave-parallel exclusive scan over the 256 per-thread counts, per class
    for (int c = wave; c < 10; c += 4) {
        int s0 = lcnt[lane*4+0][c], s1 = lcnt[lane*4+1][c];
        int s2 = lcnt[lane*4+2][c], s3 = lcnt[lane*4+3][c];
        int tot = s0 + s1 + s2 + s3;
        int incl = tot;
        #pragma unroll
        for (int d = 1; d < 64; d <<= 1) {
            int up = __shfl_up(incl, d, 64);
            if (lane >= d) incl += up;
        }
        int excl = incl - tot;
        lcnt[lane*4+0][c] = excl;
        lcnt[lane*4+1][c] = excl + s0;
        lcnt[lane*4+2][c] = excl + s0 + s1;
        lcnt[lane*4+3][c] = excl + s0 + s1 + s2;
        if (lane == 63) ccount[c] = incl;
    }
    __syncthreads();

    if (tid == 0) {
        int run = 0, runT = 0;
        for (int c = 0; c < 10; ++c) {
            cstart[c] = run; classStart[c] = run;
            int tpc = (ccount[c] + 127) >> 7;
            cumTiles[c] = runT;
            run  += ccount[c];
            runT += tpc * tpc;
        }
        cstart[10] = run; classStart[10] = run; cumTiles[10] = runT;
    }
    __syncthreads();

    int ofs[10];
    #pragma unroll
    for (int c = 0; c < 10; ++c) ofs[c] = lcnt[tid][c];
    for (int i = beg; i < end; ++i) {
        int c = label[i]; c = (c < 0) ? 0 : (c > 9 ? 9 : c);
        int pos = cstart[c] + ofs[c]++;
        perm[pos] = i;
        labelPerm[pos] = c;
    }
}

// ---------------- Kernel B: normalize + permute + bf16 cast (4 rows / block)
__global__ __launch_bounds__(256) void normalize_rows(const float* __restrict__ logits,
        const int* __restrict__ perm, ushort* __restrict__ xn)
{
    const int p = blockIdx.x * 4 + (threadIdx.x >> 6);
    const int lane = threadIdx.x & 63;
    const int old = perm[p];
    float4 v = reinterpret_cast<const float4*>(logits + (size_t)old * KDIM)[lane];
    float ss = v.x*v.x + v.y*v.y + v.z*v.z + v.w*v.w;
    #pragma unroll
    for (int off = 32; off >= 1; off >>= 1) ss += __shfl_xor(ss, off, 64);
    float inv = 1.0f / fmaxf(sqrtf(ss), 1e-8f);
    ushort4 o;
    o.x = f2bf(v.x * inv); o.y = f2bf(v.y * inv);
    o.z = f2bf(v.z * inv); o.w = f2bf(v.w * inv);
    reinterpret_cast<ushort4*>(xn + (size_t)p * KDIM)[lane] = o;
}

// ---------------- shared GEMM core: 128x128 tile, BK=64, 4 waves, T2-swizzled
// LDS chunk swizzle (rule #21): stored chunk cs = c ^ (row&7); linear LDS dest,
// pre-swizzled GLOBAL source, same XOR on ds_read.
__device__ __forceinline__ void stage_tiles(const ushort* __restrict__ xn,
        int rowBase, int colBase, int kb, ushort* As, ushort* Bs, int wave, int lane)
{
    #pragma unroll
    for (int it = 0; it < 4; ++it) {
        int ci = it * 256 + wave * 64 + lane;          // 16B chunk index in [0,1024)
        int row = ci >> 3;
        int c = (ci & 7) ^ (row & 7);                  // logical chunk for this slot
        int rowA = rowBase + row; if (rowA > N_ROWS - 1) rowA = N_ROWS - 1;
        int rowB = colBase + row; if (rowB > N_ROWS - 1) rowB = N_ROWS - 1;
        const ushort* gA = xn + (size_t)rowA * KDIM + kb + c * 8;
        const ushort* gB = xn + (size_t)rowB * KDIM + kb + c * 8;
        ushort* lA = As + (size_t)(it * 256 + wave * 64) * 8;  // wave-uniform LDS base
        ushort* lB = Bs + (size_t)(it * 256 + wave * 64) * 8;
        __builtin_amdgcn_global_load_lds((const __attribute__((address_space(1))) void*)gA,
                                         (__attribute__((address_space(3))) void*)lA, 16, 0, 0);
        __builtin_amdgcn_global_load_lds((const __attribute__((address_space(1))) void*)gB,
                                         (__attribute__((address_space(3))) void*)lB, 16, 0, 0);
    }
}

__device__ __forceinline__ void compute_step(const ushort* As, const ushort* Bs,
        f32x4 acc[4][4], int wave, int lane)
{
    const int wr = wave >> 1, wc = wave & 1;
    const int lrow = lane & 15;
    const int kgrp = lane >> 4;
    #pragma unroll
    for (int kk = 0; kk < 2; ++kk) {
        bf16x8 a[4], b[4];
        const int c = kk * 4 + kgrp;                   // logical 16B chunk
        #pragma unroll
        for (int mi = 0; mi < 4; ++mi) {
            const int row = wr*64 + mi*16 + lrow;
            a[mi] = *reinterpret_cast<const bf16x8*>(As + (size_t)row * 64 + ((c ^ (row & 7)) * 8));
        }
        #pragma unroll
        for (int ni = 0; ni < 4; ++ni) {
            const int row = wc*64 + ni*16 + lrow;
            b[ni] = *reinterpret_cast<const bf16x8*>(Bs + (size_t)row * 64 + ((c ^ (row & 7)) * 8));
        }
        #pragma unroll
        for (int mi = 0; mi < 4; ++mi)
            #pragma unroll
            for (int ni = 0; ni < 4; ++ni)
                acc[mi][ni] = __builtin_amdgcn_mfma_f32_16x16x32_bf16(a[mi], b[ni], acc[mi][ni], 0, 0, 0);
    }
}

// double-buffered K-loop (T3-minimum): issue next stage BEFORE compute
#define K_LOOP(xn, rowBase, colBase, acc, wave, lane)                              \
    stage_tiles(xn, rowBase, colBase, 0, As0, Bs0, wave, lane);                    \
    __syncthreads();                                                               \
    _Pragma("unroll")                                                              \
    for (int kt = 0; kt < 4; ++kt) {                                               \
        ushort* Ac = (kt & 1) ? As1 : As0;                                         \
        ushort* Bc = (kt & 1) ? Bs1 : Bs0;                                         \
        if (kt < 3) stage_tiles(xn, rowBase, colBase, (kt + 1) * 64,               \
                                (kt & 1) ? As0 : As1, (kt & 1) ? Bs0 : Bs1,        \
                                wave, lane);                                       \
        compute_step(Ac, Bc, acc, wave, lane);                                     \
        if (kt < 3) __syncthreads();                                               \
    }

// ---------------- Kernel C: upper-triangular tiles (bi<=bj), accumulate ONLY
// D-partials (sum of diff-label e). Off-diagonal tiles also emit column
// partials via e_ij == e_ji symmetry. Diagonal term auto-excluded (same label).
__global__ __launch_bounds__(256) void phase1_gemm(const ushort* __restrict__ xn,
        const int* __restrict__ labelPerm, float* __restrict__ pD)
{
    __shared__ __align__(16) char pool[65536];
    ushort* As0 = (ushort*)(pool);
    ushort* Bs0 = (ushort*)(pool + 16384);
    ushort* As1 = (ushort*)(pool + 32768);
    ushort* Bs1 = (ushort*)(pool + 49152);
    float* rowD = (float*)(pool);            // [128][32] f32, aliases buf0 (safe post-kt2 barrier)
    float* colD = (float*)(pool + 16384);    // [128][8]  f32
    __shared__ int rowLab[128], colLab[128];

    const int tid = threadIdx.x;
    const int wave = tid >> 6, lane = tid & 63;

    // decode upper-triangular tile index -> (bi, bj), bi <= bj
    int t = blockIdx.x, bi = 0;
    while (t >= 64 - bi) { t -= 64 - bi; ++bi; }
    const int bj = bi + t;
    const bool isDiag = (bi == bj);
    const int rowBase = bi * 128, colBase = bj * 128;

    if (tid < 128) rowLab[tid] = labelPerm[rowBase + tid];
    else           colLab[tid - 128] = labelPerm[colBase + (tid - 128)];

    f32x4 acc[4][4] = {};
    K_LOOP(xn, rowBase, colBase, acc, wave, lane);

    // ---- epilogue: exp + diff-label mask, LDS-based reductions
    const int wr = wave >> 1, wc = wave & 1;
    const int lrow = lane & 15, lgrp = lane >> 4;
    float colAcc[4] = {0.f, 0.f, 0.f, 0.f};
    #pragma unroll
    for (int mi = 0; mi < 4; ++mi) {
        #pragma unroll
        for (int reg = 0; reg < 4; ++reg) {
            const int tr = wr * 64 + mi * 16 + lgrp * 4 + reg;
            const int rl = rowLab[tr];
            float rowAcc = 0.f;
            #pragma unroll
            for (int ni = 0; ni < 4; ++ni) {
                const int tc = wc * 64 + ni * 16 + lrow;
                float e = __builtin_amdgcn_exp2f(acc[mi][ni][reg] * EXPC);
                float ed = (rl != colLab[tc]) ? e : 0.f;
                rowAcc += ed;
                colAcc[ni] += ed;
            }
            rowD[tr * 32 + wc * 16 + lrow] = rowAcc;
        }
    }
    if (!isDiag) {
        #pragma unroll
        for (int ni = 0; ni < 4; ++ni) {
            const int tc = wc * 64 + ni * 16 + lrow;
            colD[tc * 8 + wr * 4 + lgrp] = colAcc[ni];
        }
    }
    __syncthreads();

    if (tid < 128) {
        const float* p = rowD + tid * 32;
        float s = 0.f;
        #pragma unroll
        for (int k = 0; k < 8; ++k) {
            f32x4 v = *reinterpret_cast<const f32x4*>(p + k * 4);
            s += v[0] + v[1] + v[2] + v[3];
        }
        pD[(size_t)bj * N_ROWS + rowBase + tid] = s;
    } else if (!isDiag) {
        const int c2 = tid - 128;
        const float* p = colD + c2 * 8;
        f32x4 v0 = *reinterpret_cast<const f32x4*>(p);
        f32x4 v1 = *reinterpret_cast<const f32x4*>(p + 4);
        pD[(size_t)bi * N_ROWS + colBase + c2] =
            v0[0] + v0[1] + v0[2] + v0[3] + v1[0] + v1[1] + v1[2] + v1[3];
    }
}

// ---------------- Kernel C2: D_i = sum of 64 slices (deterministic fixed order)
__global__ void phase2_rowsum(const float* __restrict__ pD, float* __restrict__ Darr)
{
    const int i = blockIdx.x * blockDim.x + threadIdx.x;
    if (i >= N_ROWS) return;
    float d = 0.f;
    for (int tj = 0; tj < 64; ++tj) d += pD[(size_t)tj * N_ROWS + i];
    Darr[i] = d;
}

// ---------------- Kernel D: same-class diagonal block tiles -> log terms
__global__ __launch_bounds__(256) void phase3_loss(const ushort* __restrict__ xn,
        const float* __restrict__ Darr, const int* __restrict__ classStart,
        const int* __restrict__ cumTiles, float* __restrict__ partial)
{
    __shared__ __align__(16) char pool[65536];
    ushort* As0 = (ushort*)(pool);
    ushort* Bs0 = (ushort*)(pool + 16384);
    ushort* As1 = (ushort*)(pool + 32768);
    ushort* Bs1 = (ushort*)(pool + 49152);
    __shared__ float red[256];

    const int b = blockIdx.x;
    const int nTiles = cumTiles[10];
    if (b >= nTiles) return;

    int c = 0;
    while (c < 9 && b >= cumTiles[c + 1]) ++c;
    const int s = classStart[c], e = classStart[c + 1];
    const int nc = e - s;
    const int tps = (nc + 127) >> 7;
    const int lt = b - cumTiles[c];
    const int ti = lt / tps, tj = lt - ti * tps;
    const int rowBase = s + ti * 128, colBase = s + tj * 128;

    const int tid = threadIdx.x;
    const int wave = tid >> 6, lane = tid & 63;

    f32x4 acc[4][4] = {};
    K_LOOP(xn, rowBase, colBase, acc, wave, lane);

    const int wr = wave >> 1, wc = wave & 1;
    const int lrow = lane & 15, lgrp = lane >> 4;
    float lsum = 0.f;
    #pragma unroll
    for (int mi = 0; mi < 4; ++mi) {
        #pragma unroll
        for (int reg = 0; reg < 4; ++reg) {
            const int r = rowBase + wr * 64 + mi * 16 + lgrp * 4 + reg;
            if (r < e) {
                const float Dr = Darr[r];
                #pragma unroll
                for (int ni = 0; ni < 4; ++ni) {
                    const int cg = colBase + wc * 64 + ni * 16 + lrow;
                    if (cg < e && cg != r) {
                        float sim = acc[mi][ni][reg];
                        float ev = __builtin_amdgcn_exp2f(sim * EXPC);
                        lsum += __logf(ev + Dr) - TEMP_INV * sim;
                    }
                }
            }
        }
    }
    red[tid] = lsum;
    __syncthreads();
    for (int st = 128; st > 0; st >>= 1) {
        if (tid < st) red[tid] += red[tid + st];
        __syncthreads();
    }
    if (tid == 0) partial[b] = red[0];
}

// ---------------- Kernel E: deterministic final reduction + scale
__global__ void phase4_final(const float* __restrict__ partial, const int* __restrict__ cumTiles,
                             float* __restrict__ out)
{
    __shared__ float red[256];
    const int tid = threadIdx.x;
    const int nTiles = cumTiles[10];
    float s = 0.f;
    for (int i = tid; i < nTiles; i += 256) s += partial[i];
    red[tid] = s;
    __syncthreads();
    for (int st = 128; st > 0; st >>= 1) {
        if (tid < st) red[tid] += red[tid + st];
        __syncthreads();
    }
    if (tid == 0) out[0] = red[0] * (1.0f / 16384.0f);
}

extern "C" void kernel_launch(void* const* d_in, const int* in_sizes, int n_in,
                              void* d_out, int out_size, void* d_ws, size_t ws_size,
                              hipStream_t stream)
{
    const float* logits = (const float*)d_in[0];
    const int*   label  = (const int*)d_in[1];
    float* out = (float*)d_out;

    char* ws = (char*)d_ws;
    ushort* xn        = (ushort*)(ws);                          // 4 MB
    float*  pD        = (float*)(ws + (4u << 20));              // 2 MB
    float*  Darr      = (float*)(ws + (6u << 20));              // 32 KB
    int*    perm      = (int*)(ws + (6u << 20) + (64u << 10));  // 32 KB
    int*    labelPerm = (int*)(ws + (6u << 20) + (128u << 10)); // 32 KB
    int*    classStart= (int*)(ws + (6u << 20) + (192u << 10)); // 64 B
    int*    cumTiles  = (int*)(ws + (6u << 20) + (192u << 10) + 256); // 64 B
    float*  partial   = (float*)(ws + (6u << 20) + (256u << 10));     // 16 KB

    hipLaunchKernelGGL(build_perm, dim3(1), dim3(256), 0, stream,
                       label, perm, labelPerm, classStart, cumTiles);
    hipLaunchKernelGGL(normalize_rows, dim3(2048), dim3(256), 0, stream,
                       logits, perm, xn);
    hipLaunchKernelGGL(phase1_gemm, dim3(2080), dim3(256), 0, stream,
                       xn, labelPerm, pD);
    hipLaunchKernelGGL(phase2_rowsum, dim3(32), dim3(256), 0, stream,
                       pD, Darr);
    hipLaunchKernelGGL(phase3_loss, dim3(4096), dim3(256), 0, stream,
                       xn, Darr, classStart, cumTiles, partial);
    hipLaunchKernelGGL(phase4_final, dim3(1), dim3(256), 0, stream,
                       partial, cumTiles, out);
}